// Round 6
// baseline (181.280 us; speedup 1.0000x reference)
//
#include <hip/hip_runtime.h>
#include <hip/hip_bf16.h>

#define N 8192
#define DIMS 128
#define NSLICE 32
#define SLICE_COLS (N / NSLICE)       // 256
#define SUBTILES (SLICE_COLS / 16)    // 16
#define NSTEPS (SUBTILES / 2)         // 8 (32 cols per barrier step)
#define ROWS_PER_BLOCK 256
#define STRIPS 4                      // 16-row strips per wave (64 rows/wave)
#define NROWBLK (N / ROWS_PER_BLOCK)  // 32
#define NFIN 2048
#define MARGIN_F 0.2f
#define EPS_F 1e-6f
#define BIAS_F 512.0f                 // key' = 512 + sqj - 2dot > 0 (Cauchy-Schwarz)
#define META_LDS 32768                // after 4-deep 8KB ring
#define INF_F __builtin_huge_valf()

typedef __bf16 bf16x8 __attribute__((ext_vector_type(8)));
typedef float f32x4 __attribute__((ext_vector_type(4)));

// ws layout (bytes), ws_size = 256 MiB:
//   Xb   : ushort[N*DIMS]      @ 0          (2 MiB)   bf16 features (256B/row)
//   meta : float2[N]           @ 2097152    (64 KiB)  {sq+512, label bits}
//   part : uint2[NSLICE*N]     @ 2162688    (2 MiB)   packed {max_pos_u, min_neg_u}
//   bsum : float2[NFIN]        @ 4259840    (16 KiB)
#define XB_OFF   0
#define META_OFF 2097152
#define PART_OFF 2162688
#define BSUM_OFF 4259840

#define GLD_LDS(g, l) \
  __builtin_amdgcn_global_load_lds( \
      (const __attribute__((address_space(1))) void*)(g), \
      (__attribute__((address_space(3))) void*)(l), 16, 0, 0)

// ---------------- prep: fp32 -> bf16, row sq-norm(+bias), pack label ------
__global__ __launch_bounds__(256) void prep_kernel(
    const float* __restrict__ feat, const int* __restrict__ lab,
    unsigned short* __restrict__ Xb, float2* __restrict__ meta) {
  int row = blockIdx.x * 4 + (threadIdx.x >> 6);
  int lane = threadIdx.x & 63;
  float2 x = *reinterpret_cast<const float2*>(feat + (size_t)row * DIMS + lane * 2);
  __hip_bfloat16 hx = __float2bfloat16(x.x);
  __hip_bfloat16 hy = __float2bfloat16(x.y);
  unsigned short ux, uy;
  __builtin_memcpy(&ux, &hx, 2);
  __builtin_memcpy(&uy, &hy, 2);
  unsigned int packed = (unsigned int)ux | ((unsigned int)uy << 16);
  *reinterpret_cast<unsigned int*>(Xb + (size_t)row * DIMS + lane * 2) = packed;
  float s = x.x * x.x + x.y * x.y;
#pragma unroll
  for (int m = 32; m >= 1; m >>= 1) s += __shfl_xor(s, m, 64);
  if (lane == 0) meta[row] = make_float2(s + BIAS_F, __int_as_float(lab[row]));
}

// ---------------- mine: ring-pipelined MFMA GEMM + packed mining ----------
// grid = NROWBLK*NSLICE = 1024 blocks (3/CU), 256 threads (4 waves).
// 4-deep LDS ring of 32-col B-steps staged by global_load_lds; counted
// s_waitcnt vmcnt(N) + raw s_barrier keeps 2 steps of loads in flight
// across barriers (T3+T4). Wave owns 64 anchor rows (4 strips).
__global__ __launch_bounds__(256, 3) void mine_kernel(
    const unsigned short* __restrict__ Xb, const float2* __restrict__ meta,
    const int* __restrict__ lab, uint2* __restrict__ part) {
  __shared__ char smem[4 * 8192 + 2048];  // 4-deep ring + slice meta

  int rb = blockIdx.x / NSLICE;
  int sl = blockIdx.x % NSLICE;
  int tid = threadIdx.x;
  int wave = tid >> 6;
  int lane = tid & 63;
  int lrow = lane & 15;  // B-col / C-col lane index
  int lk = lane >> 4;    // k-subgroup; also C-row group
  int rowbase = rb * ROWS_PER_BLOCK + wave * (STRIPS * 16);
  int j0 = sl * SLICE_COLS;

  // --- stage slice meta (256 * 8B = 2KB) once: waves 0,1 ---
  if (wave < 2) {
    const char* g = (const char*)meta + (size_t)j0 * 8 + tid * 16;
    char* l = smem + META_LDS + wave * 1024;
    GLD_LDS(g, l);
  }
  // --- B staging: thread tid -> (colt = tid>>4, chunk = tid&15).
  // LDS slot col*256 + chunk*16 holds global chunk (chunk^(col&7)) of the
  // col's row (involution swizzle; col&7 invariant under +16/+32 col steps).
  int colt = tid >> 4;
  int chunk = tid & 15;
  const char* gsrc0 = (const char*)Xb + (size_t)(j0 + colt) * 256 +
                      ((chunk ^ (colt & 7)) * 16);
  // prologue: stage steps 0,1,2 into ring bufs 0,1,2
#pragma unroll
  for (int s = 0; s < 3; ++s) {
    const char* g = gsrc0 + (size_t)s * 8192;
    char* l = smem + s * 8192 + wave * 1024;
    GLD_LDS(g, l);
    GLD_LDS(g + 4096, l + 4096);
  }

  // --- A fragments: STRIPS x 4 k-groups, registers for the whole scan ---
  bf16x8 afrag[STRIPS][4];
#pragma unroll
  for (int s = 0; s < STRIPS; ++s) {
    const unsigned short* rp = Xb + (size_t)(rowbase + s * 16 + lrow) * DIMS;
#pragma unroll
    for (int g = 0; g < 4; ++g)
      afrag[s][g] = *reinterpret_cast<const bf16x8*>(rp + g * 32 + lk * 8);
  }
  int4 labi[STRIPS];
#pragma unroll
  for (int s = 0; s < STRIPS; ++s)
    labi[s] = *reinterpret_cast<const int4*>(lab + rowbase + s * 16 + lk * 4);

  unsigned int bpu[STRIPS][4], bnu[STRIPS][4];
#pragma unroll
  for (int s = 0; s < STRIPS; ++s)
#pragma unroll
    for (int e = 0; e < 4; ++e) { bpu[s][e] = 0u; bnu[s][e] = 0xFFFFFFFFu; }

  // per-lane swizzled B-frag LDS byte offsets (hoisted)
  int boff[4];
#pragma unroll
  for (int g = 0; g < 4; ++g)
    boff[g] = lrow * 256 + (((g * 4 + lk) ^ (lrow & 7)) * 16);

  __syncthreads();  // one-time full drain: meta + steps 0..2 resident,
                    // vmcnt uniform (0) across all waves from here on.

#define COMPUTE_SUBTILE(BUFOFS, T)                                           \
  {                                                                          \
    float2 mcur = *reinterpret_cast<const float2*>(                          \
        smem + META_LDS + (T) * 128 + lrow * 8);                             \
    float sqjB = mcur.x;                                                     \
    int labj = __float_as_int(mcur.y);                                       \
    unsigned int ju = (unsigned int)(j0 + (T) * 16 + lrow);                  \
    const char* bbase = smem + (BUFOFS);                                     \
    bf16x8 bb[4];                                                            \
    _Pragma("unroll") for (int g = 0; g < 4; ++g)                            \
        bb[g] = *reinterpret_cast<const bf16x8*>(bbase + boff[g]);           \
    _Pragma("unroll") for (int s = 0; s < STRIPS; ++s) {                     \
      f32x4 acc = {0.f, 0.f, 0.f, 0.f};                                      \
      _Pragma("unroll") for (int g = 0; g < 4; ++g)                          \
          acc = __builtin_amdgcn_mfma_f32_16x16x32_bf16(afrag[s][g], bb[g],  \
                                                        acc, 0, 0, 0);       \
      int labs[4] = {labi[s].x, labi[s].y, labi[s].z, labi[s].w};            \
      _Pragma("unroll") for (int e = 0; e < 4; ++e) {                        \
        float key = fmaf(-2.0f, acc[e], sqjB);                               \
        unsigned int u = (__float_as_uint(key) & 0xFFFFE000u) | ju;          \
        bool pos = (labj == labs[e]);                                        \
        unsigned int up = pos ? u : 0u;                                      \
        unsigned int un = pos ? 0xFFFFFFFFu : u;                             \
        bpu[s][e] = max(bpu[s][e], up);                                      \
        bnu[s][e] = min(bnu[s][e], un);                                      \
      }                                                                      \
    }                                                                        \
  }

  // Step IT: wait for MY step-IT loads (leave later steps in flight),
  // barrier (=> all waves' step-IT writes landed AND all readers of
  // buf[(IT-1)&3] are done), then issue prefetch of IT+3 into that buffer.
  // Outstanding before wait (steady): IT,IT+1,IT+2 = 6 loads -> vmcnt(4).
#define DO_STEP(IT, NW)                                                      \
  {                                                                          \
    asm volatile("s_waitcnt vmcnt(" #NW ")" ::: "memory");                   \
    __builtin_amdgcn_s_barrier();                                            \
    __builtin_amdgcn_sched_barrier(0);                                       \
    if ((IT) + 3 < NSTEPS) {                                                 \
      const char* g = gsrc0 + (size_t)((IT) + 3) * 8192;                     \
      char* l = smem + (((IT) + 3) & 3) * 8192 + wave * 1024;                \
      GLD_LDS(g, l);                                                         \
      GLD_LDS(g + 4096, l + 4096);                                           \
    }                                                                        \
    COMPUTE_SUBTILE(((IT) & 3) * 8192, 2 * (IT));                            \
    COMPUTE_SUBTILE(((IT) & 3) * 8192 + 4096, 2 * (IT) + 1);                 \
  }

  DO_STEP(0, 4)
  DO_STEP(1, 4)
  DO_STEP(2, 4)
  DO_STEP(3, 4)
  DO_STEP(4, 4)
  DO_STEP(5, 4)
  DO_STEP(6, 2)
  DO_STEP(7, 0)

#undef DO_STEP
#undef COMPUTE_SUBTILE

  // merge across the 16 lanes that share each C-row (lane bits 0-3)
#pragma unroll
  for (int s = 0; s < STRIPS; ++s) {
#pragma unroll
    for (int e = 0; e < 4; ++e) {
      unsigned int pu = bpu[s][e], nu = bnu[s][e];
#pragma unroll
      for (int m = 1; m < 16; m <<= 1) {
        pu = max(pu, (unsigned int)__shfl_xor((int)pu, m, 64));
        nu = min(nu, (unsigned int)__shfl_xor((int)nu, m, 64));
      }
      if (lrow == 0) {
        int row = rowbase + s * 16 + lk * 4 + e;
        part[(size_t)sl * N + row] = make_uint2(pu, nu);
      }
    }
  }
}

// ---------------- finalize: wave-per-anchor merge + exact fp32 hinge ------
__global__ __launch_bounds__(256) void finalize_kernel(
    const float* __restrict__ feat, const uint2* __restrict__ part,
    float2* __restrict__ bsum) {
  int wave = threadIdx.x >> 6, lane = threadIdx.x & 63;
  int i = blockIdx.x * 4 + wave;

  unsigned int pu = 0u, nu = 0xFFFFFFFFu;
  if (lane < NSLICE) {
    uint2 p = part[(size_t)lane * N + i];
    pu = p.x; nu = p.y;
  }
#pragma unroll
  for (int m = 1; m < 32; m <<= 1) {
    pu = max(pu, (unsigned int)__shfl_xor((int)pu, m, 64));
    nu = min(nu, (unsigned int)__shfl_xor((int)nu, m, 64));
  }
  pu = (unsigned int)__shfl((int)pu, 0, 64);
  nu = (unsigned int)__shfl((int)nu, 0, 64);
  bool valid = (nu != 0xFFFFFFFFu);
  int pi = (int)(pu & 8191u);
  int ni = (int)(nu & 8191u);

  float2 av = *reinterpret_cast<const float2*>(feat + (size_t)i * DIMS + lane * 2);
  float2 pw = *reinterpret_cast<const float2*>(feat + (size_t)pi * DIMS + lane * 2);
  float2 nw = *reinterpret_cast<const float2*>(feat + (size_t)ni * DIMS + lane * 2);
  float d0 = av.x - pw.x + EPS_F, d1 = av.y - pw.y + EPS_F;
  float sp = fmaf(d0, d0, d1 * d1);
  float e0 = av.x - nw.x + EPS_F, e1 = av.y - nw.y + EPS_F;
  float sn = fmaf(e0, e0, e1 * e1);
#pragma unroll
  for (int m = 32; m >= 1; m >>= 1) {
    sp += __shfl_xor(sp, m, 64);
    sn += __shfl_xor(sn, m, 64);
  }

  __shared__ float s_s[4], s_c[4];
  if (lane == 0) {
    float per = sqrtf(sp) - sqrtf(sn) + MARGIN_F;
    per = per > 0.f ? per : 0.f;
    per = valid ? per : 0.f;
    s_s[wave] = per;
    s_c[wave] = valid ? 1.f : 0.f;
  }
  __syncthreads();
  if (threadIdx.x == 0) {
    float ts = (s_s[0] + s_s[1]) + (s_s[2] + s_s[3]);
    float tc = (s_c[0] + s_c[1]) + (s_c[2] + s_c[3]);
    bsum[blockIdx.x] = make_float2(ts, tc);
  }
}

__global__ __launch_bounds__(256) void final_reduce_kernel(
    const float2* __restrict__ bsum, float* __restrict__ out) {
  int t = threadIdx.x;
  float s = 0.f, c = 0.f;
#pragma unroll
  for (int k = 0; k < NFIN / 256; ++k) {
    float2 v = bsum[t + k * 256];
    s += v.x; c += v.y;
  }
#pragma unroll
  for (int m = 32; m >= 1; m >>= 1) {
    s += __shfl_xor(s, m, 64);
    c += __shfl_xor(c, m, 64);
  }
  __shared__ float s_s[4], s_c[4];
  int wave = t >> 6, lane = t & 63;
  if (lane == 0) { s_s[wave] = s; s_c[wave] = c; }
  __syncthreads();
  if (t == 0) {
    float ts = (s_s[0] + s_s[1]) + (s_s[2] + s_s[3]);
    float tc = (s_c[0] + s_c[1]) + (s_c[2] + s_c[3]);
    out[0] = (tc > 0.f) ? (ts / tc) : 0.f;
  }
}

extern "C" void kernel_launch(void* const* d_in, const int* in_sizes, int n_in,
                              void* d_out, int out_size, void* d_ws, size_t ws_size,
                              hipStream_t stream) {
  const float* feat = (const float*)d_in[0];
  const int* lab = (const int*)d_in[1];
  char* ws = (char*)d_ws;
  unsigned short* Xb = (unsigned short*)(ws + XB_OFF);
  float2* meta = (float2*)(ws + META_OFF);
  uint2* part = (uint2*)(ws + PART_OFF);
  float2* bsum = (float2*)(ws + BSUM_OFF);
  float* out = (float*)d_out;

  prep_kernel<<<N / 4, 256, 0, stream>>>(feat, lab, Xb, meta);
  mine_kernel<<<NROWBLK * NSLICE, 256, 0, stream>>>(Xb, meta, lab, part);
  finalize_kernel<<<N / 4, 256, 0, stream>>>(feat, part, bsum);
  final_reduce_kernel<<<1, 256, 0, stream>>>(bsum, out);
}

// Round 8
// 179.927 us; speedup vs baseline: 1.0075x; 1.0075x over previous
//
#include <hip/hip_runtime.h>
#include <hip/hip_bf16.h>

#define N 8192
#define DIMS 128
#define NSLICE 32
#define SLICE_COLS (N / NSLICE)       // 256
#define SUBTILES (SLICE_COLS / 16)    // 16
#define NSTEPS (SUBTILES / 2)         // 8 (32 cols per barrier step)
#define ROWS_PER_BLOCK 256
#define STRIPS 4                      // 16-row strips per wave (64 rows/wave)
#define NROWBLK (N / ROWS_PER_BLOCK)  // 32
#define NFIN 2048
#define MARGIN_F 0.2f
#define EPS_F 1e-6f
#define BIAS_F 512.0f                 // key' = 512 + sqj - 2dot > 0 (Cauchy-Schwarz)
#define META_LDS 32768                // after 4-deep 8KB ring
#define INF_F __builtin_huge_valf()

typedef __bf16 bf16x8 __attribute__((ext_vector_type(8)));
typedef float f32x4 __attribute__((ext_vector_type(4)));
typedef unsigned int u32x4 __attribute__((ext_vector_type(4)));

// ws layout (bytes), ws_size = 256 MiB:
//   Xb   : ushort[N*DIMS]      @ 0          (2 MiB)   bf16 features (256B/row)
//   meta : float2[N]           @ 2097152    (64 KiB)  {sq+512, label bits}
//   part : uint2[NSLICE*N]     @ 2162688    (2 MiB)   packed {max_pos_u, min_neg_u}
//   bsum : float2[NFIN]        @ 4259840    (16 KiB)
#define XB_OFF   0
#define META_OFF 2097152
#define PART_OFF 2162688
#define BSUM_OFF 4259840

#define GLD_LDS(g, l) \
  __builtin_amdgcn_global_load_lds( \
      (const __attribute__((address_space(1))) void*)(g), \
      (__attribute__((address_space(3))) void*)(l), 16, 0, 0)

// Pin a 16-byte fragment in VGPRs at 32-bit granularity (scalar "+v" is
// supported; whole-vector "+v" is a tied indirect operand -> compile error).
// The pinned lanes' defs are opaque volatile-asm outputs => NOT
// rematerializable, so regalloc cannot re-load them from global inside the
// pipeline steps (r6 failure: 190MB HBM refetch, VGPR 84).
static __device__ __forceinline__ void pin_frag(bf16x8& v) {
  u32x4 u;
  __builtin_memcpy(&u, &v, 16);
  unsigned int a = u[0], b = u[1], c = u[2], d = u[3];
  asm volatile("" : "+v"(a), "+v"(b), "+v"(c), "+v"(d));
  u[0] = a; u[1] = b; u[2] = c; u[3] = d;
  __builtin_memcpy(&v, &u, 16);
}
static __device__ __forceinline__ void pin_int4(int4& v) {
  asm volatile("" : "+v"(v.x), "+v"(v.y), "+v"(v.z), "+v"(v.w));
}

// ---------------- prep: fp32 -> bf16, row sq-norm(+bias), pack label ------
__global__ __launch_bounds__(256) void prep_kernel(
    const float* __restrict__ feat, const int* __restrict__ lab,
    unsigned short* __restrict__ Xb, float2* __restrict__ meta) {
  int row = blockIdx.x * 4 + (threadIdx.x >> 6);
  int lane = threadIdx.x & 63;
  float2 x = *reinterpret_cast<const float2*>(feat + (size_t)row * DIMS + lane * 2);
  __hip_bfloat16 hx = __float2bfloat16(x.x);
  __hip_bfloat16 hy = __float2bfloat16(x.y);
  unsigned short ux, uy;
  __builtin_memcpy(&ux, &hx, 2);
  __builtin_memcpy(&uy, &hy, 2);
  unsigned int packed = (unsigned int)ux | ((unsigned int)uy << 16);
  *reinterpret_cast<unsigned int*>(Xb + (size_t)row * DIMS + lane * 2) = packed;
  float s = x.x * x.x + x.y * x.y;
#pragma unroll
  for (int m = 32; m >= 1; m >>= 1) s += __shfl_xor(s, m, 64);
  if (lane == 0) meta[row] = make_float2(s + BIAS_F, __int_as_float(lab[row]));
}

// ---------------- mine: ring-pipelined MFMA GEMM + packed mining ----------
// grid = NROWBLK*NSLICE = 1024 blocks (3/CU), 256 threads (4 waves).
// 4-deep LDS ring of 32-col B-steps staged by global_load_lds; counted
// s_waitcnt vmcnt(N) + raw s_barrier keeps 2 steps of loads in flight
// across barriers (T3+T4). Wave owns 64 anchor rows (4 strips, pinned regs).
__global__ __launch_bounds__(256, 3) void mine_kernel(
    const unsigned short* __restrict__ Xb, const float2* __restrict__ meta,
    const int* __restrict__ lab, uint2* __restrict__ part) {
  __shared__ char smem[4 * 8192 + 2048];  // 4-deep ring + slice meta

  int rb = blockIdx.x / NSLICE;
  int sl = blockIdx.x % NSLICE;
  int tid = threadIdx.x;
  int wave = tid >> 6;
  int lane = tid & 63;
  int lrow = lane & 15;  // B-col / C-col lane index
  int lk = lane >> 4;    // k-subgroup; also C-row group
  int rowbase = rb * ROWS_PER_BLOCK + wave * (STRIPS * 16);
  int j0 = sl * SLICE_COLS;

  // --- stage slice meta (256 * 8B = 2KB) once: waves 0,1 ---
  if (wave < 2) {
    const char* g = (const char*)meta + (size_t)j0 * 8 + tid * 16;
    char* l = smem + META_LDS + wave * 1024;
    GLD_LDS(g, l);
  }
  // --- B staging: thread tid -> (colt = tid>>4, chunk = tid&15).
  // LDS slot col*256 + chunk*16 holds global chunk (chunk^(col&7)) of the
  // col's row (involution swizzle; col&7 invariant under +16/+32 col steps).
  int colt = tid >> 4;
  int chunk = tid & 15;
  const char* gsrc0 = (const char*)Xb + (size_t)(j0 + colt) * 256 +
                      ((chunk ^ (colt & 7)) * 16);
  // prologue: stage steps 0,1,2 into ring bufs 0,1,2
#pragma unroll
  for (int s = 0; s < 3; ++s) {
    const char* g = gsrc0 + (size_t)s * 8192;
    char* l = smem + s * 8192 + wave * 1024;
    GLD_LDS(g, l);
    GLD_LDS(g + 4096, l + 4096);
  }

  // --- A fragments: STRIPS x 4 k-groups, registers for the whole scan ---
  bf16x8 afrag[STRIPS][4];
#pragma unroll
  for (int s = 0; s < STRIPS; ++s) {
    const unsigned short* rp = Xb + (size_t)(rowbase + s * 16 + lrow) * DIMS;
#pragma unroll
    for (int g = 0; g < 4; ++g) {
      afrag[s][g] = *reinterpret_cast<const bf16x8*>(rp + g * 32 + lk * 8);
      pin_frag(afrag[s][g]);  // forbid remat-from-global across steps
    }
  }
  int4 labi[STRIPS];
#pragma unroll
  for (int s = 0; s < STRIPS; ++s) {
    labi[s] = *reinterpret_cast<const int4*>(lab + rowbase + s * 16 + lk * 4);
    pin_int4(labi[s]);
  }

  unsigned int bpu[STRIPS][4], bnu[STRIPS][4];
#pragma unroll
  for (int s = 0; s < STRIPS; ++s)
#pragma unroll
    for (int e = 0; e < 4; ++e) { bpu[s][e] = 0u; bnu[s][e] = 0xFFFFFFFFu; }

  // per-lane swizzled B-frag LDS byte offsets (hoisted)
  int boff[4];
#pragma unroll
  for (int g = 0; g < 4; ++g)
    boff[g] = lrow * 256 + (((g * 4 + lk) ^ (lrow & 7)) * 16);

  __syncthreads();  // one-time full drain: meta + steps 0..2 resident,
                    // vmcnt uniform (0) across all waves from here on.

#define COMPUTE_SUBTILE(BUFOFS, T)                                           \
  {                                                                          \
    float2 mcur = *reinterpret_cast<const float2*>(                          \
        smem + META_LDS + (T) * 128 + lrow * 8);                             \
    float sqjB = mcur.x;                                                     \
    int labj = __float_as_int(mcur.y);                                       \
    unsigned int ju = (unsigned int)(j0 + (T) * 16 + lrow);                  \
    const char* bbase = smem + (BUFOFS);                                     \
    bf16x8 bb[4];                                                            \
    _Pragma("unroll") for (int g = 0; g < 4; ++g)                            \
        bb[g] = *reinterpret_cast<const bf16x8*>(bbase + boff[g]);           \
    _Pragma("unroll") for (int s = 0; s < STRIPS; ++s) {                     \
      f32x4 acc = {0.f, 0.f, 0.f, 0.f};                                      \
      _Pragma("unroll") for (int g = 0; g < 4; ++g)                          \
          acc = __builtin_amdgcn_mfma_f32_16x16x32_bf16(afrag[s][g], bb[g],  \
                                                        acc, 0, 0, 0);       \
      int labs[4] = {labi[s].x, labi[s].y, labi[s].z, labi[s].w};            \
      _Pragma("unroll") for (int e = 0; e < 4; ++e) {                        \
        float key = fmaf(-2.0f, acc[e], sqjB);                               \
        unsigned int u = (__float_as_uint(key) & 0xFFFFE000u) | ju;          \
        bool pos = (labj == labs[e]);                                        \
        unsigned int up = pos ? u : 0u;                                      \
        unsigned int un = pos ? 0xFFFFFFFFu : u;                             \
        bpu[s][e] = max(bpu[s][e], up);                                      \
        bnu[s][e] = min(bnu[s][e], un);                                      \
      }                                                                      \
    }                                                                        \
  }

  // Step IT: wait for MY step-IT loads (leave later steps in flight),
  // barrier (=> all waves' step-IT writes landed AND all readers of
  // buf[(IT-1)&3] are done), then issue prefetch of IT+3 into that buffer.
  // Outstanding before wait (steady): IT,IT+1,IT+2 = 6 loads -> vmcnt(4).
#define DO_STEP(IT, NW)                                                      \
  {                                                                          \
    asm volatile("s_waitcnt vmcnt(" #NW ")" ::: "memory");                   \
    __builtin_amdgcn_s_barrier();                                            \
    __builtin_amdgcn_sched_barrier(0);                                       \
    if ((IT) + 3 < NSTEPS) {                                                 \
      const char* g = gsrc0 + (size_t)((IT) + 3) * 8192;                     \
      char* l = smem + (((IT) + 3) & 3) * 8192 + wave * 1024;                \
      GLD_LDS(g, l);                                                         \
      GLD_LDS(g + 4096, l + 4096);                                           \
    }                                                                        \
    COMPUTE_SUBTILE(((IT) & 3) * 8192, 2 * (IT));                            \
    COMPUTE_SUBTILE(((IT) & 3) * 8192 + 4096, 2 * (IT) + 1);                 \
  }

  DO_STEP(0, 4)
  DO_STEP(1, 4)
  DO_STEP(2, 4)
  DO_STEP(3, 4)
  DO_STEP(4, 4)
  DO_STEP(5, 4)
  DO_STEP(6, 2)
  DO_STEP(7, 0)

#undef DO_STEP
#undef COMPUTE_SUBTILE

  // merge across the 16 lanes that share each C-row (lane bits 0-3)
#pragma unroll
  for (int s = 0; s < STRIPS; ++s) {
#pragma unroll
    for (int e = 0; e < 4; ++e) {
      unsigned int pu = bpu[s][e], nu = bnu[s][e];
#pragma unroll
      for (int m = 1; m < 16; m <<= 1) {
        pu = max(pu, (unsigned int)__shfl_xor((int)pu, m, 64));
        nu = min(nu, (unsigned int)__shfl_xor((int)nu, m, 64));
      }
      if (lrow == 0) {
        int row = rowbase + s * 16 + lk * 4 + e;
        part[(size_t)sl * N + row] = make_uint2(pu, nu);
      }
    }
  }
}

// ---------------- finalize: wave-per-anchor merge + exact fp32 hinge ------
__global__ __launch_bounds__(256) void finalize_kernel(
    const float* __restrict__ feat, const uint2* __restrict__ part,
    float2* __restrict__ bsum) {
  int wave = threadIdx.x >> 6, lane = threadIdx.x & 63;
  int i = blockIdx.x * 4 + wave;

  unsigned int pu = 0u, nu = 0xFFFFFFFFu;
  if (lane < NSLICE) {
    uint2 p = part[(size_t)lane * N + i];
    pu = p.x; nu = p.y;
  }
#pragma unroll
  for (int m = 1; m < 32; m <<= 1) {
    pu = max(pu, (unsigned int)__shfl_xor((int)pu, m, 64));
    nu = min(nu, (unsigned int)__shfl_xor((int)nu, m, 64));
  }
  pu = (unsigned int)__shfl((int)pu, 0, 64);
  nu = (unsigned int)__shfl((int)nu, 0, 64);
  bool valid = (nu != 0xFFFFFFFFu);
  int pi = (int)(pu & 8191u);
  int ni = (int)(nu & 8191u);

  float2 av = *reinterpret_cast<const float2*>(feat + (size_t)i * DIMS + lane * 2);
  float2 pw = *reinterpret_cast<const float2*>(feat + (size_t)pi * DIMS + lane * 2);
  float2 nw = *reinterpret_cast<const float2*>(feat + (size_t)ni * DIMS + lane * 2);
  float d0 = av.x - pw.x + EPS_F, d1 = av.y - pw.y + EPS_F;
  float sp = fmaf(d0, d0, d1 * d1);
  float e0 = av.x - nw.x + EPS_F, e1 = av.y - nw.y + EPS_F;
  float sn = fmaf(e0, e0, e1 * e1);
#pragma unroll
  for (int m = 32; m >= 1; m >>= 1) {
    sp += __shfl_xor(sp, m, 64);
    sn += __shfl_xor(sn, m, 64);
  }

  __shared__ float s_s[4], s_c[4];
  if (lane == 0) {
    float per = sqrtf(sp) - sqrtf(sn) + MARGIN_F;
    per = per > 0.f ? per : 0.f;
    per = valid ? per : 0.f;
    s_s[wave] = per;
    s_c[wave] = valid ? 1.f : 0.f;
  }
  __syncthreads();
  if (threadIdx.x == 0) {
    float ts = (s_s[0] + s_s[1]) + (s_s[2] + s_s[3]);
    float tc = (s_c[0] + s_c[1]) + (s_c[2] + s_c[3]);
    bsum[blockIdx.x] = make_float2(ts, tc);
  }
}

__global__ __launch_bounds__(256) void final_reduce_kernel(
    const float2* __restrict__ bsum, float* __restrict__ out) {
  int t = threadIdx.x;
  float s = 0.f, c = 0.f;
#pragma unroll
  for (int k = 0; k < NFIN / 256; ++k) {
    float2 v = bsum[t + k * 256];
    s += v.x; c += v.y;
  }
#pragma unroll
  for (int m = 32; m >= 1; m >>= 1) {
    s += __shfl_xor(s, m, 64);
    c += __shfl_xor(c, m, 64);
  }
  __shared__ float s_s[4], s_c[4];
  int wave = t >> 6, lane = t & 63;
  if (lane == 0) { s_s[wave] = s; s_c[wave] = c; }
  __syncthreads();
  if (t == 0) {
    float ts = (s_s[0] + s_s[1]) + (s_s[2] + s_s[3]);
    float tc = (s_c[0] + s_c[1]) + (s_c[2] + s_c[3]);
    out[0] = (tc > 0.f) ? (ts / tc) : 0.f;
  }
}

extern "C" void kernel_launch(void* const* d_in, const int* in_sizes, int n_in,
                              void* d_out, int out_size, void* d_ws, size_t ws_size,
                              hipStream_t stream) {
  const float* feat = (const float*)d_in[0];
  const int* lab = (const int*)d_in[1];
  char* ws = (char*)d_ws;
  unsigned short* Xb = (unsigned short*)(ws + XB_OFF);
  float2* meta = (float2*)(ws + META_OFF);
  uint2* part = (uint2*)(ws + PART_OFF);
  float2* bsum = (float2*)(ws + BSUM_OFF);
  float* out = (float*)d_out;

  prep_kernel<<<N / 4, 256, 0, stream>>>(feat, lab, Xb, meta);
  mine_kernel<<<NROWBLK * NSLICE, 256, 0, stream>>>(Xb, meta, lab, part);
  finalize_kernel<<<N / 4, 256, 0, stream>>>(feat, part, bsum);
  final_reduce_kernel<<<1, 256, 0, stream>>>(bsum, out);
}

// Round 9
// 47.666 us; speedup vs baseline: 3.8031x; 3.7747x over previous
//
#include <hip/hip_runtime.h>
#include <hip/hip_bf16.h>

#define N 8192
#define DIMS 128
#define NSLICE 16
#define SLICE_COLS (N / NSLICE)       // 512
#define SUBTILES (SLICE_COLS / 16)    // 32
#define NSTEPS (SUBTILES / 2)         // 16 (32 cols per barrier step)
#define ROWS_PER_BLOCK 128
#define STRIPS 2                      // 16-row strips per wave (32 rows/wave)
#define NROWBLK (N / ROWS_PER_BLOCK)  // 64
#define NFIN 2048
#define MARGIN_F 0.2f
#define EPS_F 1e-6f
#define BIAS_F 512.0f                 // key' = 512 + sqj - 2dot > 0 (Cauchy-Schwarz)
#define META_LDS 32768                // after 4-deep 8KB ring
#define INF_F __builtin_huge_valf()

typedef __bf16 bf16x8 __attribute__((ext_vector_type(8)));
typedef float f32x4 __attribute__((ext_vector_type(4)));

// ws layout (bytes), ws_size = 256 MiB:
//   Xb   : ushort[N*DIMS]      @ 0          (2 MiB)   bf16 features (256B/row)
//   meta : float2[N]           @ 2097152    (64 KiB)  {sq+512, label bits}
//   part : uint2[NSLICE*N]     @ 2162688    (1 MiB)   packed {max_pos_u, min_neg_u}
//   bsum : float2[NFIN]        @ 4259840    (16 KiB)
#define XB_OFF   0
#define META_OFF 2097152
#define PART_OFF 2162688
#define BSUM_OFF 4259840

#define GLD_LDS(g, l) \
  __builtin_amdgcn_global_load_lds( \
      (const __attribute__((address_space(1))) void*)(g), \
      (__attribute__((address_space(3))) void*)(l), 16, 0, 0)

// ---------------- prep: fp32 -> bf16, row sq-norm(+bias), pack label ------
__global__ __launch_bounds__(256) void prep_kernel(
    const float* __restrict__ feat, const int* __restrict__ lab,
    unsigned short* __restrict__ Xb, float2* __restrict__ meta) {
  int row = blockIdx.x * 4 + (threadIdx.x >> 6);
  int lane = threadIdx.x & 63;
  float2 x = *reinterpret_cast<const float2*>(feat + (size_t)row * DIMS + lane * 2);
  __hip_bfloat16 hx = __float2bfloat16(x.x);
  __hip_bfloat16 hy = __float2bfloat16(x.y);
  unsigned short ux, uy;
  __builtin_memcpy(&ux, &hx, 2);
  __builtin_memcpy(&uy, &hy, 2);
  unsigned int packed = (unsigned int)ux | ((unsigned int)uy << 16);
  *reinterpret_cast<unsigned int*>(Xb + (size_t)row * DIMS + lane * 2) = packed;
  float s = x.x * x.x + x.y * x.y;
#pragma unroll
  for (int m = 32; m >= 1; m >>= 1) s += __shfl_xor(s, m, 64);
  if (lane == 0) meta[row] = make_float2(s + BIAS_F, __int_as_float(lab[row]));
}

// ---------------- mine: ring-pipelined MFMA GEMM + packed mining ----------
// grid = NROWBLK*NSLICE = 1024 blocks (4/CU), 256 threads (4 waves).
// 4-deep LDS ring of 32-col B-steps staged via global_load_lds; counted
// s_waitcnt vmcnt(4) + s_barrier (both "memory"-clobbered asm = compiler
// fences, scheduler otherwise free) keeps 2 steps of loads in flight across
// barriers. STRIPS=2 keeps live set ~105 VGPR < 128 cap (r6/r8 lesson:
// STRIPS=4 + pinned schedule exceeded the cap -> 400MB scratch traffic).
__global__ __launch_bounds__(256, 4) void mine_kernel(
    const unsigned short* __restrict__ Xb, const float2* __restrict__ meta,
    const int* __restrict__ lab, uint2* __restrict__ part) {
  __shared__ char smem[4 * 8192 + 4096];  // 4-deep ring + slice meta (4KB)

  int rb = blockIdx.x / NSLICE;
  int sl = blockIdx.x % NSLICE;
  int tid = threadIdx.x;
  int wave = tid >> 6;
  int lane = tid & 63;
  int lrow = lane & 15;  // B-col / C-col lane index
  int lk = lane >> 4;    // k-subgroup; also C-row group
  int rowbase = rb * ROWS_PER_BLOCK + wave * (STRIPS * 16);
  int j0 = sl * SLICE_COLS;

  // --- stage slice meta (512 * 8B = 4KB) once, all 4 waves ---
  {
    const char* g = (const char*)meta + (size_t)j0 * 8 + tid * 16;
    char* l = smem + META_LDS + wave * 1024;
    GLD_LDS(g, l);
  }
  // --- B staging: thread tid -> (colt = tid>>4, chunk = tid&15).
  // LDS slot col*256 + chunk*16 holds global chunk (chunk^(col&7)) of the
  // col's row (involution swizzle; col&7 invariant under +16/+32 col steps).
  int colt = tid >> 4;
  int chunk = tid & 15;
  const char* gsrc0 = (const char*)Xb + (size_t)(j0 + colt) * 256 +
                      ((chunk ^ (colt & 7)) * 16);
  // prologue: stage steps 0,1,2 into ring bufs 0,1,2
#pragma unroll
  for (int s = 0; s < 3; ++s) {
    const char* g = gsrc0 + (size_t)s * 8192;
    char* l = smem + s * 8192 + wave * 1024;
    GLD_LDS(g, l);
    GLD_LDS(g + 4096, l + 4096);
  }

  // --- A fragments: STRIPS x 4 k-groups, registers for the whole scan ---
  bf16x8 afrag[STRIPS][4];
#pragma unroll
  for (int s = 0; s < STRIPS; ++s) {
    const unsigned short* rp = Xb + (size_t)(rowbase + s * 16 + lrow) * DIMS;
#pragma unroll
    for (int g = 0; g < 4; ++g)
      afrag[s][g] = *reinterpret_cast<const bf16x8*>(rp + g * 32 + lk * 8);
  }
  int4 labi[STRIPS];
#pragma unroll
  for (int s = 0; s < STRIPS; ++s)
    labi[s] = *reinterpret_cast<const int4*>(lab + rowbase + s * 16 + lk * 4);

  unsigned int bpu[STRIPS][4], bnu[STRIPS][4];
#pragma unroll
  for (int s = 0; s < STRIPS; ++s)
#pragma unroll
    for (int e = 0; e < 4; ++e) { bpu[s][e] = 0u; bnu[s][e] = 0xFFFFFFFFu; }

  // per-lane swizzled B-frag LDS byte offsets (hoisted)
  int boff[4];
#pragma unroll
  for (int g = 0; g < 4; ++g)
    boff[g] = lrow * 256 + (((g * 4 + lk) ^ (lrow & 7)) * 16);

  __syncthreads();  // one-time full drain: meta + steps 0..2 resident,
                    // vmcnt uniform (0) across all waves from here on.

  // Per step: barrier (step's buffer resident for ALL waves, and all
  // readers of buf[(it-1)&3] done) -> prefetch step it+3 into that buffer
  // -> compute 2 subtiles. The preceding counted waitcnt drained exactly
  // this step's 2 loads (issued 3 steps ago) while leaving 4 in flight.
#define STEP_BODY(IT)                                                        \
  {                                                                          \
    asm volatile("s_barrier" ::: "memory");                                  \
    if ((IT) + 3 < NSTEPS) {                                                 \
      const char* g = gsrc0 + (size_t)((IT) + 3) * 8192;                     \
      char* l = smem + (((IT) + 3) & 3) * 8192 + wave * 1024;                \
      GLD_LDS(g, l);                                                         \
      GLD_LDS(g + 4096, l + 4096);                                           \
    }                                                                        \
    _Pragma("unroll") for (int h = 0; h < 2; ++h) {                          \
      int t = (IT) * 2 + h;                                                  \
      float2 mcur = *reinterpret_cast<const float2*>(                        \
          smem + META_LDS + t * 128 + lrow * 8);                             \
      float sqjB = mcur.x;                                                   \
      int labj = __float_as_int(mcur.y);                                     \
      unsigned int ju = (unsigned int)(j0 + t * 16 + lrow);                  \
      const char* bbase = smem + ((IT) & 3) * 8192 + h * 4096;               \
      bf16x8 bb[4];                                                          \
      _Pragma("unroll") for (int g = 0; g < 4; ++g)                          \
          bb[g] = *reinterpret_cast<const bf16x8*>(bbase + boff[g]);         \
      _Pragma("unroll") for (int s = 0; s < STRIPS; ++s) {                   \
        f32x4 acc = {0.f, 0.f, 0.f, 0.f};                                    \
        _Pragma("unroll") for (int g = 0; g < 4; ++g)                        \
            acc = __builtin_amdgcn_mfma_f32_16x16x32_bf16(afrag[s][g],       \
                                                          bb[g], acc,        \
                                                          0, 0, 0);          \
        int labs[4] = {labi[s].x, labi[s].y, labi[s].z, labi[s].w};          \
        _Pragma("unroll") for (int e = 0; e < 4; ++e) {                      \
          float key = fmaf(-2.0f, acc[e], sqjB);                             \
          unsigned int u = (__float_as_uint(key) & 0xFFFFE000u) | ju;        \
          bool pos = (labj == labs[e]);                                      \
          unsigned int up = pos ? u : 0u;                                    \
          unsigned int un = pos ? 0xFFFFFFFFu : u;                           \
          bpu[s][e] = max(bpu[s][e], up);                                    \
          bnu[s][e] = min(bnu[s][e], un);                                    \
        }                                                                    \
      }                                                                      \
    }                                                                        \
  }

  // steady state: 6 loads outstanding before wait -> keep 4 in flight
  for (int it = 0; it < NSTEPS - 2; ++it) {
    asm volatile("s_waitcnt vmcnt(4)" ::: "memory");
    STEP_BODY(it);
  }
  asm volatile("s_waitcnt vmcnt(2)" ::: "memory");
  STEP_BODY(NSTEPS - 2);
  asm volatile("s_waitcnt vmcnt(0)" ::: "memory");
  STEP_BODY(NSTEPS - 1);
#undef STEP_BODY

  // merge across the 16 lanes that share each C-row (lane bits 0-3)
#pragma unroll
  for (int s = 0; s < STRIPS; ++s) {
#pragma unroll
    for (int e = 0; e < 4; ++e) {
      unsigned int pu = bpu[s][e], nu = bnu[s][e];
#pragma unroll
      for (int m = 1; m < 16; m <<= 1) {
        pu = max(pu, (unsigned int)__shfl_xor((int)pu, m, 64));
        nu = min(nu, (unsigned int)__shfl_xor((int)nu, m, 64));
      }
      if (lrow == 0) {
        int row = rowbase + s * 16 + lk * 4 + e;
        part[(size_t)sl * N + row] = make_uint2(pu, nu);
      }
    }
  }
}

// ---------------- finalize: wave-per-anchor merge + exact fp32 hinge ------
__global__ __launch_bounds__(256) void finalize_kernel(
    const float* __restrict__ feat, const uint2* __restrict__ part,
    float2* __restrict__ bsum) {
  int wave = threadIdx.x >> 6, lane = threadIdx.x & 63;
  int i = blockIdx.x * 4 + wave;

  unsigned int pu = 0u, nu = 0xFFFFFFFFu;
  if (lane < NSLICE) {
    uint2 p = part[(size_t)lane * N + i];
    pu = p.x; nu = p.y;
  }
#pragma unroll
  for (int m = 1; m < NSLICE; m <<= 1) {
    pu = max(pu, (unsigned int)__shfl_xor((int)pu, m, 64));
    nu = min(nu, (unsigned int)__shfl_xor((int)nu, m, 64));
  }
  pu = (unsigned int)__shfl((int)pu, 0, 64);
  nu = (unsigned int)__shfl((int)nu, 0, 64);
  bool valid = (nu != 0xFFFFFFFFu);
  int pi = (int)(pu & 8191u);
  int ni = (int)(nu & 8191u);

  float2 av = *reinterpret_cast<const float2*>(feat + (size_t)i * DIMS + lane * 2);
  float2 pw = *reinterpret_cast<const float2*>(feat + (size_t)pi * DIMS + lane * 2);
  float2 nw = *reinterpret_cast<const float2*>(feat + (size_t)ni * DIMS + lane * 2);
  float d0 = av.x - pw.x + EPS_F, d1 = av.y - pw.y + EPS_F;
  float sp = fmaf(d0, d0, d1 * d1);
  float e0 = av.x - nw.x + EPS_F, e1 = av.y - nw.y + EPS_F;
  float sn = fmaf(e0, e0, e1 * e1);
#pragma unroll
  for (int m = 32; m >= 1; m >>= 1) {
    sp += __shfl_xor(sp, m, 64);
    sn += __shfl_xor(sn, m, 64);
  }

  __shared__ float s_s[4], s_c[4];
  if (lane == 0) {
    float per = sqrtf(sp) - sqrtf(sn) + MARGIN_F;
    per = per > 0.f ? per : 0.f;
    per = valid ? per : 0.f;
    s_s[wave] = per;
    s_c[wave] = valid ? 1.f : 0.f;
  }
  __syncthreads();
  if (threadIdx.x == 0) {
    float ts = (s_s[0] + s_s[1]) + (s_s[2] + s_s[3]);
    float tc = (s_c[0] + s_c[1]) + (s_c[2] + s_c[3]);
    bsum[blockIdx.x] = make_float2(ts, tc);
  }
}

__global__ __launch_bounds__(256) void final_reduce_kernel(
    const float2* __restrict__ bsum, float* __restrict__ out) {
  int t = threadIdx.x;
  float s = 0.f, c = 0.f;
#pragma unroll
  for (int k = 0; k < NFIN / 256; ++k) {
    float2 v = bsum[t + k * 256];
    s += v.x; c += v.y;
  }
#pragma unroll
  for (int m = 32; m >= 1; m >>= 1) {
    s += __shfl_xor(s, m, 64);
    c += __shfl_xor(c, m, 64);
  }
  __shared__ float s_s[4], s_c[4];
  int wave = t >> 6, lane = t & 63;
  if (lane == 0) { s_s[wave] = s; s_c[wave] = c; }
  __syncthreads();
  if (t == 0) {
    float ts = (s_s[0] + s_s[1]) + (s_s[2] + s_s[3]);
    float tc = (s_c[0] + s_c[1]) + (s_c[2] + s_c[3]);
    out[0] = (tc > 0.f) ? (ts / tc) : 0.f;
  }
}

extern "C" void kernel_launch(void* const* d_in, const int* in_sizes, int n_in,
                              void* d_out, int out_size, void* d_ws, size_t ws_size,
                              hipStream_t stream) {
  const float* feat = (const float*)d_in[0];
  const int* lab = (const int*)d_in[1];
  char* ws = (char*)d_ws;
  unsigned short* Xb = (unsigned short*)(ws + XB_OFF);
  float2* meta = (float2*)(ws + META_OFF);
  uint2* part = (uint2*)(ws + PART_OFF);
  float2* bsum = (float2*)(ws + BSUM_OFF);
  float* out = (float*)d_out;

  prep_kernel<<<N / 4, 256, 0, stream>>>(feat, lab, Xb, meta);
  mine_kernel<<<NROWBLK * NSLICE, 256, 0, stream>>>(Xb, meta, lab, part);
  finalize_kernel<<<N / 4, 256, 0, stream>>>(feat, part, bsum);
  final_reduce_kernel<<<1, 256, 0, stream>>>(bsum, out);
}